// Round 6
// baseline (296.332 us; speedup 1.0000x reference)
//
#include <hip/hip_runtime.h>
#include <hip/hip_bf16.h>
#include <cstdint>

// MFVI second-order CRF, B=32 S=1024 T=256 W=2 ITER=3.
// msg = Shift(P) @ Wc, M=32768 N=256 K=1024 (4 shift regions).
// Round 11: LDS-traffic cut. Iter kernel was LDS-pipe-bound (~21us of LDS
// work vs 4us MFMA): waves 0-3 read duplicate A (4x), pairs (w,w+4)
// duplicate B (2x). New geometry: M-tile 128 x N 256 per block, 8 waves as
// 2M x 4N of 64x64 wave-tiles -> ds_read per output x2/3, B-staging per
// output halved. Grid 256 = 1 block/CU, LDS 102KB, VGPR cap 256 via
// launch_bounds(512,2). K-loop keeps round-10 counted-vmcnt schedule
// (vmcnt(2) rides 2 DMA loads across barriers; never drained in-loop).
//
// ws: Pa bf16 [32][1028][256] @0 | Pb @32MB | WcTt bf16 [32][1024]x16B @64MB

typedef __attribute__((ext_vector_type(4))) float f32x4;
typedef __attribute__((ext_vector_type(8))) short bf16x8;

__device__ __forceinline__ void load_lds16(const void* g, void* l) {
    __builtin_amdgcn_global_load_lds(
        (const __attribute__((address_space(1))) void*)g,
        (__attribute__((address_space(3))) void*)l, 16, 0, 0);
}

// ---------------- prep: tiled+pre-swizzled WcT build + guard rows -----------
// WcTt chunk (p, sl): sl = n*4 + cs holds global k-chunk gk = p*4 +
// (cs ^ ((n>>1)&3)) of logical WcT row n (matches K-loop B-read involution).
__global__ __launch_bounds__(256) void prep_wct(
    const float* __restrict__ trans,
    __hip_bfloat16* __restrict__ Pa, __hip_bfloat16* __restrict__ Pb,
    __hip_bfloat16* __restrict__ WcTt)
{
    int idx = blockIdx.x * 256 + threadIdx.x;
    if (idx < 32768) {
        int p = idx >> 10, sl = idx & 1023;
        int n = sl >> 2, cs = sl & 3;
        int gk = p * 4 + (cs ^ ((n >> 1) & 3));
        union { bf16x8 v; __hip_bfloat16 h[8]; } o;
        #pragma unroll
        for (int e = 0; e < 8; ++e) {
            int k = gk * 8 + e;
            int r = k >> 8, kk = k & 255;
            float v;
            if (r == 0)      v = trans[kk * 256 + n];
            else if (r == 1) v = trans[65536 + kk * 256 + n];
            else if (r == 2) v = trans[n * 256 + kk];
            else             v = trans[65536 + n * 256 + kk];
            o.h[e] = __float2bfloat16(v);
        }
        ((bf16x8*)WcTt)[idx] = o.v;
    } else if (idx < 40960) {
        // zero guard rows (0,1,1026,1027) of Pa and Pb, 16B chunks
        int g = idx - 32768;
        __hip_bfloat16* P = (g & 4096) ? Pb : Pa;
        int rem = g & 4095;
        int b = rem >> 7, wr = (rem >> 5) & 3, ch = rem & 31;
        int row = b * 1028 + ((wr < 2) ? wr : 1024 + wr);
        bf16x8 z = {};
        *(bf16x8*)(P + row * 256 + ch * 8) = z;
    }
}

// ---------------- iteration kernel -----------------------------------------
// Block: 512 threads = 8 waves. M-tile 128 x N 256. Wave w: rows
// (w>>2)*64..+63, cols (w&3)*64..+63 (64x64 wave tile, acc[4][4]).
// Ps (A, 132x256 swizzled) staged once; Bs double-buffered counted-vmcnt.
__global__ __launch_bounds__(512, 2) void mfvi_iter_k(
    const __hip_bfloat16* __restrict__ Pin,   // [32][1028][256] padded
    const __hip_bfloat16* __restrict__ WcTt,  // [32][1024] x 16B tiles
    const float* __restrict__ unary, const int* __restrict__ lengths,
    const float* __restrict__ startT, const float* __restrict__ endT,
    __hip_bfloat16* __restrict__ Pout, float* __restrict__ out,
    int first_it, int final_it)
{
    __shared__ __hip_bfloat16 Ps[132 * 256];      // 67584 B
    __shared__ __hip_bfloat16 Bs[2 * 256 * 32];   // 2 x 16384 B
    __shared__ float redA[512];                   // [nslice][row 0..127]
    __shared__ float redB[512];                   // total 104448 B -> 1 blk/CU

    int tid = threadIdx.x;
    int lane = tid & 63, w = tid >> 6;
    int cn = lane & 15, quad = lane >> 4;
    int wm = (w >> 2) * 64, wn = (w & 3) * 64;
    int nslice = w & 3;
    int tile = blockIdx.x;                        // 0..255
    int b = tile >> 3, s0 = (tile & 7) << 7;
    int len = lengths[b];

    if (first_it) {
        // ---- prologue: P row r (padded 0..131) = softmax(masked unary row
        // s0+r-2), bf16 into swizzled Ps.
        for (int q = 0; q < 17; ++q) {
            int r = w + q * 8;
            if (r >= 132) break;
            int s = s0 + r - 2;
            int ch = lane >> 1;
            int slot = (ch & ~7) | ((ch ^ r) & 7);
            char* dst = (char*)Ps + r * 512 + slot * 16 + (lane & 1) * 8;
            if (s >= 0 && s < 1024) {
                float mval = (s < len) ? 1.f : 0.f;
                float4 x = *((const float4*)(unary + ((size_t)((b << 10) + s)) * 256 + lane * 4));
                x.x *= mval; x.y *= mval; x.z *= mval; x.w *= mval;
                float mx = fmaxf(fmaxf(x.x, x.y), fmaxf(x.z, x.w));
                #pragma unroll
                for (int o = 32; o; o >>= 1) mx = fmaxf(mx, __shfl_xor(mx, o));
                float ea = __expf(x.x - mx), eb = __expf(x.y - mx);
                float ec = __expf(x.z - mx), ed = __expf(x.w - mx);
                float sum = ea + eb + ec + ed;
                #pragma unroll
                for (int o = 32; o; o >>= 1) sum += __shfl_xor(sum, o);
                float inv = 1.0f / sum;
                union { ushort4 u; __hip_bfloat16 h[4]; } o4;
                o4.h[0] = __float2bfloat16(ea * inv);
                o4.h[1] = __float2bfloat16(eb * inv);
                o4.h[2] = __float2bfloat16(ec * inv);
                o4.h[3] = __float2bfloat16(ed * inv);
                *((ushort4*)dst) = o4.u;
            } else {
                ushort4 z = {0, 0, 0, 0};
                *((ushort4*)dst) = z;
            }
        }
    } else {
        // ---- stage Ps via DMA: rows s0-2..s0+129 (padded 0..131), 256 cols.
        // 132x32 = 4224 chunks. LDS slot c=row*32+ch holds global chunk
        // (ch&~7)|((ch^row)&7).
        const char* Pbase = (const char*)(Pin + ((size_t)b * 1028 + s0) * 256);
        #pragma unroll
        for (int t = 0; t < 9; ++t) {
            int c = t * 512 + tid;
            if (t < 8 || tid < 128) {
                int row = c >> 5, ch = c & 31;
                int gch = (ch & ~7) | ((ch ^ row) & 7);
                load_lds16(Pbase + row * 512 + gch * 16, (char*)Ps + c * 16);
            }
        }
    }
    __syncthreads();          // drains prologue (Ps writes / Ps DMA)

    // Bs stage for K-step p into buffer bb: linear coalesced 16KB DMA of the
    // pre-swizzled tile (2 chunks/thread).
    auto stageB = [&](int bb, int p) {
        #pragma unroll
        for (int c = 0; c < 2; ++c) {
            int sl = c * 512 + tid;
            load_lds16((const char*)WcTt + p * 16384 + sl * 16,
                       (char*)Bs + bb * 16384 + sl * 16);
        }
    };

    stageB(0, 0);
    stageB(1, 1);             // 4 loads/thread in flight entering the loop

    f32x4 acc[4][4] = {};

// ---- counted-vmcnt K-step (round-10 schedule). Reads of Bs[p&1] complete
// (lgkmcnt0 + barrier) before the overwrite stage(p+2) is issued; MFMA
// overlaps that DMA.
#define K_STEP(P, VMC, DOSTAGE) do {                                         \
    asm volatile("s_waitcnt vmcnt(" #VMC ")" ::: "memory");                  \
    __builtin_amdgcn_s_barrier();                                            \
    int region = (P) >> 3;                                                   \
    int delta = (region == 0) ? -1 : (region == 1) ? -2                      \
              : (region == 2) ?  1 : 2;                                      \
    int gcb = ((P) & 7) * 4 + quad;                                          \
    bf16x8 af[4], bfv[4];                                                    \
    _Pragma("unroll")                                                        \
    for (int i = 0; i < 4; ++i) {                                            \
        int r = wm + (i << 4) + cn + delta + 2;                              \
        int slot = (gcb & ~7) | ((gcb ^ r) & 7);                             \
        af[i] = *(const bf16x8*)((const char*)Ps + r * 512 + slot * 16);     \
    }                                                                        \
    _Pragma("unroll")                                                        \
    for (int j = 0; j < 4; ++j) {                                            \
        int n = wn + (j << 4) + cn;                                          \
        int cs = quad ^ ((n >> 1) & 3);                                      \
        bfv[j] = *(const bf16x8*)((const char*)Bs + ((P) & 1) * 16384        \
                                  + n * 64 + cs * 16);                       \
    }                                                                        \
    asm volatile("s_waitcnt lgkmcnt(0)" ::: "memory");                       \
    __builtin_amdgcn_s_barrier();                                            \
    if (DOSTAGE) stageB(((P) & 1), (P) + 2);                                 \
    __builtin_amdgcn_s_setprio(1);                                           \
    _Pragma("unroll")                                                        \
    for (int i = 0; i < 4; ++i)                                              \
        _Pragma("unroll")                                                    \
        for (int j = 0; j < 4; ++j)                                          \
            acc[i][j] = __builtin_amdgcn_mfma_f32_16x16x32_bf16(             \
                af[i], bfv[j], acc[i][j], 0, 0, 0);                          \
    __builtin_amdgcn_s_setprio(0);                                           \
} while (0)

    #pragma unroll
    for (int p = 0; p < 30; ++p) K_STEP(p, 2, true);
    K_STEP(30, 2, false);
    K_STEP(31, 0, false);
#undef K_STEP

    // ---- boundary + unary + mask. C/D: col=lane&15, row=quad*4+reg
    #pragma unroll
    for (int i = 0; i < 4; ++i)
        #pragma unroll
        for (int j = 0; j < 4; ++j) {
            int n = wn + (j << 4) + cn;
            #pragma unroll
            for (int r = 0; r < 4; ++r) {
                int s = s0 + wm + (i << 4) + (quad << 2) + r;
                float x = acc[i][j][r];
                if (s == 0)       x += startT[n];
                if (s == 1)       x += startT[256 + n];
                if (s == len - 1) x += endT[n];
                if (s == len - 2) x += endT[256 + n];
                long idx = ((long)((b << 10) + s)) * 256 + n;
                x += unary[idx];
                acc[i][j][r] = (s < len) ? x : 0.f;
            }
        }

    if (final_it) {
        #pragma unroll
        for (int i = 0; i < 4; ++i)
            #pragma unroll
            for (int j = 0; j < 4; ++j) {
                int n = wn + (j << 4) + cn;
                #pragma unroll
                for (int r = 0; r < 4; ++r) {
                    int s = s0 + wm + (i << 4) + (quad << 2) + r;
                    out[((long)((b << 10) + s)) * 256 + n] = acc[i][j][r];
                }
            }
        return;
    }

    // ---- fused row softmax over 256 cols (quad shfl-reduce + LDS combine)
    // redA[nslice][row 0..127]
    #pragma unroll
    for (int i = 0; i < 4; ++i)
        #pragma unroll
        for (int r = 0; r < 4; ++r) {
            float m4 = fmaxf(fmaxf(acc[i][0][r], acc[i][1][r]),
                             fmaxf(acc[i][2][r], acc[i][3][r]));
            m4 = fmaxf(m4, __shfl_xor(m4, 1));
            m4 = fmaxf(m4, __shfl_xor(m4, 2));
            m4 = fmaxf(m4, __shfl_xor(m4, 4));
            m4 = fmaxf(m4, __shfl_xor(m4, 8));
            if (cn == 0)
                redA[(nslice << 7) + wm + (i << 4) + (quad << 2) + r] = m4;
        }
    __syncthreads();
    float M[4][4];
    #pragma unroll
    for (int i = 0; i < 4; ++i)
        #pragma unroll
        for (int r = 0; r < 4; ++r) {
            int row = wm + (i << 4) + (quad << 2) + r;
            M[i][r] = fmaxf(fmaxf(redA[row], redA[128 + row]),
                            fmaxf(redA[256 + row], redA[384 + row]));
        }
    #pragma unroll
    for (int i = 0; i < 4; ++i)
        #pragma unroll
        for (int r = 0; r < 4; ++r) {
            float s4 = 0.f;
            #pragma unroll
            for (int j = 0; j < 4; ++j) {
                float e = __expf(acc[i][j][r] - M[i][r]);
                acc[i][j][r] = e;
                s4 += e;
            }
            s4 += __shfl_xor(s4, 1);
            s4 += __shfl_xor(s4, 2);
            s4 += __shfl_xor(s4, 4);
            s4 += __shfl_xor(s4, 8);
            if (cn == 0)
                redB[(nslice << 7) + wm + (i << 4) + (quad << 2) + r] = s4;
        }
    __syncthreads();
    #pragma unroll
    for (int i = 0; i < 4; ++i)
        #pragma unroll
        for (int r = 0; r < 4; ++r) {
            int row = wm + (i << 4) + (quad << 2) + r;
            float inv = 1.0f / (redB[row] + redB[128 + row] +
                                redB[256 + row] + redB[384 + row]);
            int s = s0 + row;
            #pragma unroll
            for (int j = 0; j < 4; ++j) {
                int n = wn + (j << 4) + cn;
                Pout[((size_t)b * 1028 + 2 + s) * 256 + n] =
                    __float2bfloat16(acc[i][j][r] * inv);
            }
        }
}

extern "C" void kernel_launch(void* const* d_in, const int* in_sizes, int n_in,
                              void* d_out, int out_size, void* d_ws, size_t ws_size,
                              hipStream_t stream) {
    const float* unary  = (const float*)d_in[1];
    const float* trans  = (const float*)d_in[3];
    const float* startT = (const float*)d_in[4];
    const float* endT   = (const float*)d_in[5];
    const int*   lens   = (const int*)d_in[6];

    char* ws = (char*)d_ws;
    __hip_bfloat16* Pa   = (__hip_bfloat16*)ws;                          // 16.8 MB
    __hip_bfloat16* Pb   = (__hip_bfloat16*)(ws + ((size_t)32 << 20));   // 16.8 MB
    __hip_bfloat16* WcTt = (__hip_bfloat16*)(ws + ((size_t)64 << 20));   // 512 KB
    float* out = (float*)d_out;

    prep_wct<<<dim3(160), dim3(256), 0, stream>>>(trans, Pa, Pb, WcTt);
    mfvi_iter_k<<<dim3(256), dim3(512), 0, stream>>>(Pa, WcTt, unary, lens, startT, endT, Pb, nullptr, 1, 0);
    mfvi_iter_k<<<dim3(256), dim3(512), 0, stream>>>(Pb, WcTt, unary, lens, startT, endT, Pa, nullptr, 0, 0);
    mfvi_iter_k<<<dim3(256), dim3(512), 0, stream>>>(Pa, WcTt, unary, lens, startT, endT, nullptr, out, 0, 1);
}